// Round 1
// baseline (749.010 us; speedup 1.0000x reference)
//
#include <hip/hip_runtime.h>
#include <stdint.h>

// SVDQW4A4Linear on MI355X.
// Pipeline:
//   k_wdq   : B'[o][0:4096]    = bf16(qweight * wscale)           (weight dequant)
//   k_wlora : B'[o][4096:4160] = bf16(proj_up) | zeros            (K-extension for LoRA-up)
//   k_prep  : pdT[r][k] = bf16(proj_down^T), rsmooth = 1/smooth
//   k_quant : A'[t][0:4096]    = bf16(xdq)  (exact fp32 quant path), zeros pad 4128:4160
//   k_lora  : A'[t][4096:4128] = bf16(xs @ proj_down)  (MFMA, xs recomputed as x*rsmooth)
//   k_gemm  : out = A' @ B'^T  (m97-style 128x128 tile, BK=64, global_load_lds w16,
//                               16x16x32 bf16 MFMA, 4 waves x 4x4 tiles)
// Workspace: A' 68.2MB + B' 34.1MB + pdT 0.26MB + rsmooth 16KB = 102.5 MB

#define T_DIM 8192
#define IN_DIM 4096
#define OUT_DIM 4096
#define RANK 32
#define KP 4160       // 4096 main + 32 lora + 32 zero pad -> 65 iters of BK=64
#define LORA_OFF 4096
#define ZPAD_OFF 4128

typedef unsigned short u16;
typedef __attribute__((ext_vector_type(8))) short short8;
typedef __attribute__((ext_vector_type(4))) float f32x4;
typedef __attribute__((address_space(1))) const unsigned int gas_u32;
typedef __attribute__((address_space(3))) unsigned int las_u32;

__device__ __forceinline__ u16 f2bf(float f) {
  unsigned u = __float_as_uint(f);
  u += 0x7FFFu + ((u >> 16) & 1u);   // round-to-nearest-even; inputs are finite normals
  return (u16)(u >> 16);
}

// ---------------- weight dequant into B' ----------------
__global__ __launch_bounds__(256) void k_wdq(const int* __restrict__ qw,
                                             const float* __restrict__ wsc,
                                             u16* __restrict__ B) {
  int o = blockIdx.x >> 2;
  int k0 = ((blockIdx.x & 3) * 256 + threadIdx.x) * 4;
  int4 q = *(const int4*)(qw + (size_t)o * IN_DIM + k0);
  float s = wsc[(k0 >> 6) * OUT_DIM + o];   // wscales[g][o], all 4 k in same group
  ushort4 r;
  r.x = f2bf((float)q.x * s);
  r.y = f2bf((float)q.y * s);
  r.z = f2bf((float)q.z * s);
  r.w = f2bf((float)q.w * s);
  *(ushort4*)(B + (size_t)o * KP + k0) = r;
}

// ---------------- proj_up + zero pad into B' ----------------
__global__ __launch_bounds__(256) void k_wlora(const float* __restrict__ pu,
                                               u16* __restrict__ B) {
  int id = blockIdx.x * 256 + threadIdx.x;   // 4096*64
  int o = id >> 6, c = id & 63;
  u16 v = 0;
  if (c < RANK) v = f2bf(pu[o * RANK + c]);
  B[(size_t)o * KP + LORA_OFF + c] = v;
}

// ---------------- proj_down transpose (bf16) + reciprocal smooth ----------------
__global__ __launch_bounds__(256) void k_prep(const float* __restrict__ pd,
                                              const float* __restrict__ smooth,
                                              u16* __restrict__ pdT,
                                              float* __restrict__ rs) {
  int id = blockIdx.x * 256 + threadIdx.x;   // 4096*32 = 131072 -> 512 blocks
  int k = id >> 5, r = id & 31;
  pdT[(size_t)r * IN_DIM + k] = f2bf(pd[(size_t)k * RANK + r]);
  if (id < IN_DIM) rs[id] = 1.0f / smooth[id];
}

// ---------------- activation quantization (exact fp32 path) ----------------
// One wave per token. Lane l, chunk c: k0 = c*256 + l*4 -> 16 lanes cover one
// group of 64; shfl_xor max-reduce over the 16-lane subset gives group amax.
__global__ __launch_bounds__(256) void k_quant(const float* __restrict__ x,
                                               const float* __restrict__ smooth,
                                               u16* __restrict__ A) {
  int wave = threadIdx.x >> 6;
  int lane = threadIdx.x & 63;
  int t = blockIdx.x * 4 + wave;
  const float* xrow = x + (size_t)t * IN_DIM;
  u16* arow = A + (size_t)t * KP;
  for (int c = 0; c < 16; ++c) {
    int k0 = c * 256 + lane * 4;
    float4 xv = *(const float4*)(xrow + k0);
    float4 sv = *(const float4*)(smooth + k0);
    float a0 = xv.x / sv.x;            // IEEE div: matches reference xs exactly
    float a1 = xv.y / sv.y;
    float a2 = xv.z / sv.z;
    float a3 = xv.w / sv.w;
    float m = fmaxf(fmaxf(fabsf(a0), fabsf(a1)), fmaxf(fabsf(a2), fabsf(a3)));
    m = fmaxf(m, __shfl_xor(m, 1));
    m = fmaxf(m, __shfl_xor(m, 2));
    m = fmaxf(m, __shfl_xor(m, 4));
    m = fmaxf(m, __shfl_xor(m, 8));    // group amax in all 16 lanes
    float ascale = m / 7.0f;           // IEEE div: matches reference
    if (ascale == 0.0f) ascale = 1.0f;
    float q0 = fminf(7.0f, fmaxf(-8.0f, rintf(a0 / ascale)));  // rint = half-even
    float q1 = fminf(7.0f, fmaxf(-8.0f, rintf(a1 / ascale)));
    float q2 = fminf(7.0f, fmaxf(-8.0f, rintf(a2 / ascale)));
    float q3 = fminf(7.0f, fmaxf(-8.0f, rintf(a3 / ascale)));
    ushort4 o;
    o.x = f2bf(q0 * ascale);
    o.y = f2bf(q1 * ascale);
    o.z = f2bf(q2 * ascale);
    o.w = f2bf(q3 * ascale);
    *(ushort4*)(arow + k0) = o;
  }
  // zero pad cols 4128..4159 (32 ushorts = 64B): 8 lanes x 8B
  if (lane < 8) *(uint2*)(arow + ZPAD_OFF + lane * 4) = make_uint2(0u, 0u);
}

// ---------------- lora_act = xs @ proj_down, written into A'[.,4096:4128] ----------------
// Block = 4 waves, each wave 16 tokens x 32 ranks, full K=4096.
__global__ __launch_bounds__(256) void k_lora(const float* __restrict__ x,
                                              const float* __restrict__ rs,
                                              const u16* __restrict__ pdT,
                                              u16* __restrict__ A) {
  __shared__ float sr[IN_DIM];
  for (int i = threadIdx.x; i < IN_DIM / 4; i += 256)
    ((float4*)sr)[i] = ((const float4*)rs)[i];
  __syncthreads();
  int wave = threadIdx.x >> 6, lane = threadIdx.x & 63;
  int quad = lane >> 4, l16 = lane & 15;
  int t0 = blockIdx.x * 64 + wave * 16;
  int tA = t0 + l16;
  f32x4 acc0 = {0.f, 0.f, 0.f, 0.f}, acc1 = {0.f, 0.f, 0.f, 0.f};
  const float* xrow = x + (size_t)tA * IN_DIM;
  for (int k0 = 0; k0 < IN_DIM; k0 += 32) {
    int kq = k0 + quad * 8;
    float4 xa = *(const float4*)(xrow + kq);
    float4 xb = *(const float4*)(xrow + kq + 4);
    float4 ra = *(const float4*)(sr + kq);
    float4 rb = *(const float4*)(sr + kq + 4);
    short8 a;
    a[0] = (short)f2bf(xa.x * ra.x);
    a[1] = (short)f2bf(xa.y * ra.y);
    a[2] = (short)f2bf(xa.z * ra.z);
    a[3] = (short)f2bf(xa.w * ra.w);
    a[4] = (short)f2bf(xb.x * rb.x);
    a[5] = (short)f2bf(xb.y * rb.y);
    a[6] = (short)f2bf(xb.z * rb.z);
    a[7] = (short)f2bf(xb.w * rb.w);
    short8 b0 = *(const short8*)(pdT + (size_t)l16 * IN_DIM + kq);
    short8 b1 = *(const short8*)(pdT + (size_t)(16 + l16) * IN_DIM + kq);
    acc0 = __builtin_amdgcn_mfma_f32_16x16x32_bf16(a, b0, acc0, 0, 0, 0);
    acc1 = __builtin_amdgcn_mfma_f32_16x16x32_bf16(a, b1, acc1, 0, 0, 0);
  }
  // C layout: col = lane&15 (rank), row = quad*4 + e (token)
  for (int e = 0; e < 4; ++e) {
    int trow = t0 + quad * 4 + e;
    A[(size_t)trow * KP + LORA_OFF + l16] = f2bf(acc0[e]);
    A[(size_t)trow * KP + LORA_OFF + 16 + l16] = f2bf(acc1[e]);
  }
}

// ---------------- main GEMM: out[T][OUT] = A'[T][KP] @ B'[OUT][KP]^T ----------------
__global__ __launch_bounds__(256) void k_gemm(const u16* __restrict__ A,
                                              const u16* __restrict__ B,
                                              float* __restrict__ C) {
  __shared__ u16 sA[128 * 64];
  __shared__ u16 sB[128 * 64];
  int tid = threadIdx.x;
  int wave = tid >> 6, lane = tid & 63;
  int quad = lane >> 4, l16 = lane & 15;
  int wr = wave >> 1, wc = wave & 1;
  int t0 = blockIdx.x * 128;
  int o0 = blockIdx.y * 128;
  f32x4 acc[4][4];
  for (int i = 0; i < 4; ++i)
    for (int j = 0; j < 4; ++j)
      acc[i][j] = (f32x4){0.f, 0.f, 0.f, 0.f};
  const u16* gA = A + (size_t)t0 * KP;
  const u16* gB = B + (size_t)o0 * KP;
  for (int k0 = 0; k0 < KP; k0 += 64) {
    __syncthreads();   // protect LDS from previous iteration's readers
#pragma unroll
    for (int r = 0; r < 4; ++r) {
      int off = r * 4096 + wave * 1024 + lane * 16;  // byte offset in 16KB tile
      int row = off >> 7;                            // 128B per row (64 bf16)
      int kw = (off & 127) >> 1;                     // ushort index within row
      __builtin_amdgcn_global_load_lds(
          (gas_u32*)(const void*)(gA + (size_t)row * KP + k0 + kw),
          (las_u32*)(void*)((char*)sA + off), 16, 0, 0);
      __builtin_amdgcn_global_load_lds(
          (gas_u32*)(const void*)(gB + (size_t)row * KP + k0 + kw),
          (las_u32*)(void*)((char*)sB + off), 16, 0, 0);
    }
    __syncthreads();
#pragma unroll
    for (int kk = 0; kk < 2; ++kk) {
      short8 af[4], bf[4];
#pragma unroll
      for (int i = 0; i < 4; ++i)
        af[i] = *(const short8*)(sA + (wr * 64 + i * 16 + l16) * 64 + kk * 32 + quad * 8);
#pragma unroll
      for (int j = 0; j < 4; ++j)
        bf[j] = *(const short8*)(sB + (wc * 64 + j * 16 + l16) * 64 + kk * 32 + quad * 8);
#pragma unroll
      for (int i = 0; i < 4; ++i)
#pragma unroll
        for (int j = 0; j < 4; ++j)
          acc[i][j] = __builtin_amdgcn_mfma_f32_16x16x32_bf16(af[i], bf[j], acc[i][j], 0, 0, 0);
    }
  }
  // epilogue: C row = token (quad*4+e), col = out channel (lane&15)
#pragma unroll
  for (int i = 0; i < 4; ++i) {
    int row = t0 + wr * 64 + i * 16 + quad * 4;
#pragma unroll
    for (int j = 0; j < 4; ++j) {
      int col = o0 + wc * 64 + j * 16 + l16;
#pragma unroll
      for (int e = 0; e < 4; ++e)
        C[(size_t)(row + e) * OUT_DIM + col] = acc[i][j][e];
    }
  }
}

extern "C" void kernel_launch(void* const* d_in, const int* in_sizes, int n_in,
                              void* d_out, int out_size, void* d_ws, size_t ws_size,
                              hipStream_t stream) {
  const float* x      = (const float*)d_in[0];
  const int*   qw     = (const int*)d_in[1];
  const float* wsc    = (const float*)d_in[2];
  const float* smooth = (const float*)d_in[3];
  const float* pd     = (const float*)d_in[4];
  const float* pu     = (const float*)d_in[5];
  float* out = (float*)d_out;

  char* ws = (char*)d_ws;
  u16* A   = (u16*)ws;                                   // 8192*4160*2 = 68,157,440
  u16* B   = (u16*)(ws + 68157440);                      // 4096*4160*2 = 34,078,720
  u16* pdT = (u16*)(ws + 68157440 + 34078720);           // 262,144
  float* rs = (float*)(ws + 68157440 + 34078720 + 262144); // 16,384

  k_wdq  <<<dim3(OUT_DIM * 4), dim3(256), 0, stream>>>(qw, wsc, B);
  k_wlora<<<dim3(OUT_DIM * 64 / 256), dim3(256), 0, stream>>>(pu, B);
  k_prep <<<dim3(IN_DIM * RANK / 256), dim3(256), 0, stream>>>(pd, smooth, pdT, rs);
  k_quant<<<dim3(T_DIM / 4), dim3(256), 0, stream>>>(x, smooth, A);
  k_lora <<<dim3(T_DIM / 64), dim3(256), 0, stream>>>(x, rs, pdT, A);
  k_gemm <<<dim3(T_DIM / 128, OUT_DIM / 128), dim3(256), 0, stream>>>(A, B, out);
}

// Round 2
// 679.280 us; speedup vs baseline: 1.1027x; 1.1027x over previous
//
#include <hip/hip_runtime.h>
#include <stdint.h>

// SVDQW4A4Linear on MI355X.
// R2: XOR-swizzled LDS in k_gemm (kills 16-way bank conflicts: row stride was
//     128B = 32 banks, quad's 16 lanes collided; chunk' = chunk ^ (row&7)
//     spreads starts across all 32 banks, leaving only the free 2-way alias).
//     k_lora restructured to split-K (512 blocks x 4 waves, K=1024/wave,
//     LDS reduce) -- was 128 blocks on 256 CUs.
// Pipeline:
//   k_wdq   : B'[o][0:4096]    = bf16(qweight * wscale)
//   k_wlora : B'[o][4096:4160] = bf16(proj_up) | zeros
//   k_prep  : pdT[r][k] = bf16(proj_down^T), rsmooth = 1/smooth
//   k_quant : A'[t][0:4096]    = bf16(xdq) exact fp32 quant path; zero pad
//   k_lora  : A'[t][4096:4128] = bf16(xs @ proj_down)   (split-K MFMA)
//   k_gemm  : out = A' @ B'^T  (128x128 tile, BK=64, global_load_lds w16,
//                               16x16x32 bf16 MFMA, XOR-swizzled LDS)

#define T_DIM 8192
#define IN_DIM 4096
#define OUT_DIM 4096
#define RANK 32
#define KP 4160
#define LORA_OFF 4096
#define ZPAD_OFF 4128

typedef unsigned short u16;
typedef __attribute__((ext_vector_type(8))) short short8;
typedef __attribute__((ext_vector_type(4))) float f32x4;
typedef __attribute__((address_space(1))) const unsigned int gas_u32;
typedef __attribute__((address_space(3))) unsigned int las_u32;

__device__ __forceinline__ u16 f2bf(float f) {
  unsigned u = __float_as_uint(f);
  u += 0x7FFFu + ((u >> 16) & 1u);   // RNE; inputs finite
  return (u16)(u >> 16);
}

// ---------------- weight dequant into B' ----------------
__global__ __launch_bounds__(256) void k_wdq(const int* __restrict__ qw,
                                             const float* __restrict__ wsc,
                                             u16* __restrict__ B) {
  int o = blockIdx.x >> 2;
  int k0 = ((blockIdx.x & 3) * 256 + threadIdx.x) * 4;
  int4 q = *(const int4*)(qw + (size_t)o * IN_DIM + k0);
  float s = wsc[(k0 >> 6) * OUT_DIM + o];
  ushort4 r;
  r.x = f2bf((float)q.x * s);
  r.y = f2bf((float)q.y * s);
  r.z = f2bf((float)q.z * s);
  r.w = f2bf((float)q.w * s);
  *(ushort4*)(B + (size_t)o * KP + k0) = r;
}

// ---------------- proj_up + zero pad into B' ----------------
__global__ __launch_bounds__(256) void k_wlora(const float* __restrict__ pu,
                                               u16* __restrict__ B) {
  int id = blockIdx.x * 256 + threadIdx.x;   // 4096*64
  int o = id >> 6, c = id & 63;
  u16 v = 0;
  if (c < RANK) v = f2bf(pu[o * RANK + c]);
  B[(size_t)o * KP + LORA_OFF + c] = v;
}

// ---------------- proj_down transpose (bf16) + reciprocal smooth ----------------
__global__ __launch_bounds__(256) void k_prep(const float* __restrict__ pd,
                                              const float* __restrict__ smooth,
                                              u16* __restrict__ pdT,
                                              float* __restrict__ rs) {
  int id = blockIdx.x * 256 + threadIdx.x;   // 131072
  int k = id >> 5, r = id & 31;
  pdT[(size_t)r * IN_DIM + k] = f2bf(pd[(size_t)k * RANK + r]);
  if (id < IN_DIM) rs[id] = 1.0f / smooth[id];
}

// ---------------- activation quantization (exact fp32 path) ----------------
__global__ __launch_bounds__(256) void k_quant(const float* __restrict__ x,
                                               const float* __restrict__ smooth,
                                               u16* __restrict__ A) {
  int wave = threadIdx.x >> 6;
  int lane = threadIdx.x & 63;
  int t = blockIdx.x * 4 + wave;
  const float* xrow = x + (size_t)t * IN_DIM;
  u16* arow = A + (size_t)t * KP;
  for (int c = 0; c < 16; ++c) {
    int k0 = c * 256 + lane * 4;
    float4 xv = *(const float4*)(xrow + k0);
    float4 sv = *(const float4*)(smooth + k0);
    float a0 = xv.x / sv.x;            // IEEE div: matches reference xs
    float a1 = xv.y / sv.y;
    float a2 = xv.z / sv.z;
    float a3 = xv.w / sv.w;
    float m = fmaxf(fmaxf(fabsf(a0), fabsf(a1)), fmaxf(fabsf(a2), fabsf(a3)));
    m = fmaxf(m, __shfl_xor(m, 1));
    m = fmaxf(m, __shfl_xor(m, 2));
    m = fmaxf(m, __shfl_xor(m, 4));
    m = fmaxf(m, __shfl_xor(m, 8));
    float ascale = m / 7.0f;
    if (ascale == 0.0f) ascale = 1.0f;
    float q0 = fminf(7.0f, fmaxf(-8.0f, rintf(a0 / ascale)));
    float q1 = fminf(7.0f, fmaxf(-8.0f, rintf(a1 / ascale)));
    float q2 = fminf(7.0f, fmaxf(-8.0f, rintf(a2 / ascale)));
    float q3 = fminf(7.0f, fmaxf(-8.0f, rintf(a3 / ascale)));
    ushort4 o;
    o.x = f2bf(q0 * ascale);
    o.y = f2bf(q1 * ascale);
    o.z = f2bf(q2 * ascale);
    o.w = f2bf(q3 * ascale);
    *(ushort4*)(arow + k0) = o;
  }
  if (lane < 8) *(uint2*)(arow + ZPAD_OFF + lane * 4) = make_uint2(0u, 0u);
}

// ---------------- lora_act = xs @ proj_down (split-K across 4 waves) ----------------
// Block = 16 tokens; wave w covers K in [w*1024,(w+1)*1024); LDS reduce.
__global__ __launch_bounds__(256) void k_lora(const float* __restrict__ x,
                                              const float* __restrict__ rs,
                                              const u16* __restrict__ pdT,
                                              u16* __restrict__ A) {
  __shared__ float sacc[4][16][32];   // 8 KB
  int wave = threadIdx.x >> 6, lane = threadIdx.x & 63;
  int quad = lane >> 4, l16 = lane & 15;
  int t0 = blockIdx.x * 16;
  const float* xrow = x + (size_t)(t0 + l16) * IN_DIM;
  f32x4 acc0 = {0.f, 0.f, 0.f, 0.f}, acc1 = {0.f, 0.f, 0.f, 0.f};
  int kbase = wave * 1024;
  for (int it = 0; it < 32; ++it) {
    int kq = kbase + it * 32 + quad * 8;
    float4 xa = *(const float4*)(xrow + kq);
    float4 xb = *(const float4*)(xrow + kq + 4);
    float4 ra = *(const float4*)(rs + kq);
    float4 rb = *(const float4*)(rs + kq + 4);
    short8 a;
    a[0] = (short)f2bf(xa.x * ra.x);
    a[1] = (short)f2bf(xa.y * ra.y);
    a[2] = (short)f2bf(xa.z * ra.z);
    a[3] = (short)f2bf(xa.w * ra.w);
    a[4] = (short)f2bf(xb.x * rb.x);
    a[5] = (short)f2bf(xb.y * rb.y);
    a[6] = (short)f2bf(xb.z * rb.z);
    a[7] = (short)f2bf(xb.w * rb.w);
    short8 b0 = *(const short8*)(pdT + (size_t)l16 * IN_DIM + kq);
    short8 b1 = *(const short8*)(pdT + (size_t)(16 + l16) * IN_DIM + kq);
    acc0 = __builtin_amdgcn_mfma_f32_16x16x32_bf16(a, b0, acc0, 0, 0, 0);
    acc1 = __builtin_amdgcn_mfma_f32_16x16x32_bf16(a, b1, acc1, 0, 0, 0);
  }
  // C layout: col=l16 (rank), row=quad*4+e (token)
  for (int e = 0; e < 4; ++e) {
    sacc[wave][quad * 4 + e][l16] = acc0[e];
    sacc[wave][quad * 4 + e][16 + l16] = acc1[e];
  }
  __syncthreads();
  for (int t = threadIdx.x; t < 512; t += 256) {
    int row = t >> 5, rk = t & 31;
    float s = sacc[0][row][rk] + sacc[1][row][rk] + sacc[2][row][rk] + sacc[3][row][rk];
    A[(size_t)(t0 + row) * KP + LORA_OFF + rk] = f2bf(s);
  }
}

// ---------------- main GEMM: out = A'[T][KP] @ B'[OUT][KP]^T ----------------
// XOR-swizzled LDS: row r, 16B-chunk c stored at chunk slot c^(r&7).
__global__ __launch_bounds__(256) void k_gemm(const u16* __restrict__ A,
                                              const u16* __restrict__ B,
                                              float* __restrict__ C) {
  __shared__ u16 sA[128 * 64];
  __shared__ u16 sB[128 * 64];
  int tid = threadIdx.x;
  int wave = tid >> 6, lane = tid & 63;
  int quad = lane >> 4, l16 = lane & 15;
  int wr = wave >> 1, wc = wave & 1;
  int t0 = blockIdx.x * 128;
  int o0 = blockIdx.y * 128;
  f32x4 acc[4][4];
  for (int i = 0; i < 4; ++i)
    for (int j = 0; j < 4; ++j)
      acc[i][j] = (f32x4){0.f, 0.f, 0.f, 0.f};
  const u16* gA = A + (size_t)t0 * KP;
  const u16* gB = B + (size_t)o0 * KP;
  for (int k0 = 0; k0 < KP; k0 += 64) {
    __syncthreads();
#pragma unroll
    for (int r = 0; r < 4; ++r) {
      int off = r * 4096 + wave * 1024 + lane * 16;  // LDS byte offset
      int row = off >> 7;                            // 128B rows
      int sc = ((off >> 4) & 7) ^ (row & 7);         // swizzled source chunk
      int kw = sc * 8;                               // ushort index within row
      __builtin_amdgcn_global_load_lds(
          (gas_u32*)(const void*)(gA + (size_t)row * KP + k0 + kw),
          (las_u32*)(void*)((char*)sA + off), 16, 0, 0);
      __builtin_amdgcn_global_load_lds(
          (gas_u32*)(const void*)(gB + (size_t)row * KP + k0 + kw),
          (las_u32*)(void*)((char*)sB + off), 16, 0, 0);
    }
    __syncthreads();
#pragma unroll
    for (int kk = 0; kk < 2; ++kk) {
      short8 af[4], bf[4];
#pragma unroll
      for (int i = 0; i < 4; ++i) {
        int row = wr * 64 + i * 16 + l16;
        int sc = (kk * 4 + quad) ^ (l16 & 7);
        af[i] = *(const short8*)(sA + row * 64 + sc * 8);
      }
#pragma unroll
      for (int j = 0; j < 4; ++j) {
        int row = wc * 64 + j * 16 + l16;
        int sc = (kk * 4 + quad) ^ (l16 & 7);
        bf[j] = *(const short8*)(sB + row * 64 + sc * 8);
      }
#pragma unroll
      for (int i = 0; i < 4; ++i)
#pragma unroll
        for (int j = 0; j < 4; ++j)
          acc[i][j] = __builtin_amdgcn_mfma_f32_16x16x32_bf16(af[i], bf[j], acc[i][j], 0, 0, 0);
    }
  }
#pragma unroll
  for (int i = 0; i < 4; ++i) {
    int row = t0 + wr * 64 + i * 16 + quad * 4;
#pragma unroll
    for (int j = 0; j < 4; ++j) {
      int col = o0 + wc * 64 + j * 16 + l16;
#pragma unroll
      for (int e = 0; e < 4; ++e)
        C[(size_t)(row + e) * OUT_DIM + col] = acc[i][j][e];
    }
  }
}

extern "C" void kernel_launch(void* const* d_in, const int* in_sizes, int n_in,
                              void* d_out, int out_size, void* d_ws, size_t ws_size,
                              hipStream_t stream) {
  const float* x      = (const float*)d_in[0];
  const int*   qw     = (const int*)d_in[1];
  const float* wsc    = (const float*)d_in[2];
  const float* smooth = (const float*)d_in[3];
  const float* pd     = (const float*)d_in[4];
  const float* pu     = (const float*)d_in[5];
  float* out = (float*)d_out;

  char* ws = (char*)d_ws;
  u16* A   = (u16*)ws;                                     // 68,157,440 B
  u16* B   = (u16*)(ws + 68157440);                        // 34,078,720 B
  u16* pdT = (u16*)(ws + 68157440 + 34078720);             // 262,144 B
  float* rs = (float*)(ws + 68157440 + 34078720 + 262144); // 16,384 B

  k_wdq  <<<dim3(OUT_DIM * 4), dim3(256), 0, stream>>>(qw, wsc, B);
  k_wlora<<<dim3(OUT_DIM * 64 / 256), dim3(256), 0, stream>>>(pu, B);
  k_prep <<<dim3(IN_DIM * RANK / 256), dim3(256), 0, stream>>>(pd, smooth, pdT, rs);
  k_quant<<<dim3(T_DIM / 4), dim3(256), 0, stream>>>(x, smooth, A);
  k_lora <<<dim3(T_DIM / 16), dim3(256), 0, stream>>>(x, rs, pdT, A);
  k_gemm <<<dim3(T_DIM / 128, OUT_DIM / 128), dim3(256), 0, stream>>>(A, B, out);
}

// Round 3
// 670.159 us; speedup vs baseline: 1.1177x; 1.0136x over previous
//
#include <hip/hip_runtime.h>
#include <stdint.h>

// SVDQW4A4Linear on MI355X.
// R3: fuse k_quant + k_lora into k_act — x read ONCE coalesced; exact IEEE
//     quant in registers; bf16(xs) staged to XOR-swizzled LDS; 4 waves do
//     split-K MFMA for lora_act against L2-hot pdT. Eliminates the second
//     134MB x pass and the 16-row scattered x loads of old k_lora.
//     k_gemm unchanged from R2 (conflict-free swizzled LDS, 701 TF).
// Pipeline:
//   k_wdq   : B'[o][0:4096]    = bf16(qweight * wscale)
//   k_wlora : B'[o][4096:4160] = bf16(proj_up) | zeros
//   k_prep  : pdT[r][k] = bf16(proj_down^T)
//   k_act   : A'[t][0:4096] = bf16(xdq), A'[t][4096:4128] = bf16(xs@proj_down),
//             A'[t][4128:4160] = 0
//   k_gemm  : out = A' @ B'^T (128x128 tile, BK=64, global_load_lds w16,
//             16x16x32 bf16 MFMA, XOR-swizzled LDS)

#define T_DIM 8192
#define IN_DIM 4096
#define OUT_DIM 4096
#define RANK 32
#define KP 4160
#define LORA_OFF 4096
#define ZPAD_OFF 4128
#define CHUNK 512
#define NCHUNK 8   // IN_DIM / CHUNK

typedef unsigned short u16;
typedef __attribute__((ext_vector_type(8))) short short8;
typedef __attribute__((ext_vector_type(4))) float f32x4;
typedef __attribute__((address_space(1))) const unsigned int gas_u32;
typedef __attribute__((address_space(3))) unsigned int las_u32;

__device__ __forceinline__ u16 f2bf(float f) {
  unsigned u = __float_as_uint(f);
  u += 0x7FFFu + ((u >> 16) & 1u);   // RNE; inputs finite
  return (u16)(u >> 16);
}

// ---------------- weight dequant into B' ----------------
__global__ __launch_bounds__(256) void k_wdq(const int* __restrict__ qw,
                                             const float* __restrict__ wsc,
                                             u16* __restrict__ B) {
  int o = blockIdx.x >> 2;
  int k0 = ((blockIdx.x & 3) * 256 + threadIdx.x) * 4;
  int4 q = *(const int4*)(qw + (size_t)o * IN_DIM + k0);
  float s = wsc[(k0 >> 6) * OUT_DIM + o];
  ushort4 r;
  r.x = f2bf((float)q.x * s);
  r.y = f2bf((float)q.y * s);
  r.z = f2bf((float)q.z * s);
  r.w = f2bf((float)q.w * s);
  *(ushort4*)(B + (size_t)o * KP + k0) = r;
}

// ---------------- proj_up + zero pad into B' ----------------
__global__ __launch_bounds__(256) void k_wlora(const float* __restrict__ pu,
                                               u16* __restrict__ B) {
  int id = blockIdx.x * 256 + threadIdx.x;   // 4096*64
  int o = id >> 6, c = id & 63;
  u16 v = 0;
  if (c < RANK) v = f2bf(pu[o * RANK + c]);
  B[(size_t)o * KP + LORA_OFF + c] = v;
}

// ---------------- proj_down transpose (bf16) ----------------
__global__ __launch_bounds__(256) void k_prep(const float* __restrict__ pd,
                                              u16* __restrict__ pdT) {
  int id = blockIdx.x * 256 + threadIdx.x;   // 131072
  int k = id >> 5, r = id & 31;
  pdT[(size_t)r * IN_DIM + k] = f2bf(pd[(size_t)k * RANK + r]);
}

// ---------------- fused activation quant + lora_down ----------------
// Block: 256 threads, 16 tokens, full K=4096 in chunks of 512.
// Staging role: thread t -> token row = t>>4, 32 contiguous cols (t&15)*32
//   within the chunk (coalesced x/smooth loads, coalesced A' stores).
// LDS: sxs[16 rows][64 chunks of 8 bf16], slot = c ^ (row&7)  (conflict-free
//   on both store and read phases: 8 distinct bank-starts x 4 banks).
// MFMA role: wave w covers chunk-cols [w*128,(w+1)*128); split-K reduce at end.
__global__ __launch_bounds__(256) void k_act(const float* __restrict__ x,
                                             const float* __restrict__ smooth,
                                             const u16* __restrict__ pdT,
                                             u16* __restrict__ A) {
  __shared__ u16 sxs[16 * 512];        // 16 KB
  __shared__ float sacc[4][16][32];    // 8 KB
  int tid = threadIdx.x;
  int wave = tid >> 6, lane = tid & 63;
  int quad = lane >> 4, l16 = lane & 15;
  int t0 = blockIdx.x * 16;
  int row = tid >> 4;                  // staging token row
  int seg = tid & 15;                  // 32-col segment in chunk
  const float* xrow = x + (size_t)(t0 + row) * IN_DIM;
  u16* arow = A + (size_t)(t0 + row) * KP;

  f32x4 acc0 = {0.f, 0.f, 0.f, 0.f}, acc1 = {0.f, 0.f, 0.f, 0.f};

  for (int it = 0; it < NCHUNK; ++it) {
    int cbase = it * CHUNK;
    int c0 = cbase + seg * 32;
    float xs[32];
#pragma unroll
    for (int j = 0; j < 8; ++j) {
      float4 xv = *(const float4*)(xrow + c0 + j * 4);
      float4 sv = *(const float4*)(smooth + c0 + j * 4);
      xs[j * 4 + 0] = xv.x / sv.x;     // IEEE div: matches reference xs
      xs[j * 4 + 1] = xv.y / sv.y;
      xs[j * 4 + 2] = xv.z / sv.z;
      xs[j * 4 + 3] = xv.w / sv.w;
    }
    float m = 0.f;
#pragma unroll
    for (int j = 0; j < 32; ++j) m = fmaxf(m, fabsf(xs[j]));
    m = fmaxf(m, __shfl_xor(m, 1));    // pair covers the 64-col group
    float ascale = m / 7.0f;           // IEEE div: matches reference
    if (ascale == 0.0f) ascale = 1.0f;

    __syncthreads();                   // prev chunk's MFMA readers done
#pragma unroll
    for (int j = 0; j < 4; ++j) {      // 4 chunks of 8 bf16
      short8 w8, s8;
#pragma unroll
      for (int e = 0; e < 8; ++e) {
        float a = xs[j * 8 + e];
        float q = fminf(7.0f, fmaxf(-8.0f, rintf(a / ascale)));  // half-even
        w8[e] = (short)f2bf(q * ascale);
        s8[e] = (short)f2bf(a);
      }
      *(short8*)(arow + c0 + j * 8) = w8;                 // xdq -> A'
      int c = seg * 4 + j;
      int slot = c ^ (row & 7);
      *(short8*)((char*)sxs + (row * 64 + slot) * 16) = s8;  // xs -> LDS
    }
    __syncthreads();
#pragma unroll
    for (int kk = 0; kk < 4; ++kk) {
      int crel = wave * 16 + kk * 4 + quad;    // 8-col chunk index in chunk
      int slot = crel ^ (l16 & 7);
      short8 af = *(const short8*)((const char*)sxs + (l16 * 64 + slot) * 16);
      int kg = cbase + wave * 128 + kk * 32 + quad * 8;
      short8 b0 = *(const short8*)(pdT + (size_t)l16 * IN_DIM + kg);
      short8 b1 = *(const short8*)(pdT + (size_t)(16 + l16) * IN_DIM + kg);
      acc0 = __builtin_amdgcn_mfma_f32_16x16x32_bf16(af, b0, acc0, 0, 0, 0);
      acc1 = __builtin_amdgcn_mfma_f32_16x16x32_bf16(af, b1, acc1, 0, 0, 0);
    }
  }
  // split-K reduce across waves; C layout: col=l16 (rank), row=quad*4+e (token)
#pragma unroll
  for (int e = 0; e < 4; ++e) {
    sacc[wave][quad * 4 + e][l16] = acc0[e];
    sacc[wave][quad * 4 + e][16 + l16] = acc1[e];
  }
  __syncthreads();
  for (int t = tid; t < 512; t += 256) {
    int r2 = t >> 5, rk = t & 31;
    float s = sacc[0][r2][rk] + sacc[1][r2][rk] + sacc[2][r2][rk] + sacc[3][r2][rk];
    A[(size_t)(t0 + r2) * KP + LORA_OFF + rk] = f2bf(s);
  }
  // zero pad cols 4128..4159: 16 rows x 32 cols, 2 u16 per thread
  {
    int r2 = tid >> 4, c2 = (tid & 15) * 2;
    *(unsigned*)(A + (size_t)(t0 + r2) * KP + ZPAD_OFF + c2) = 0u;
  }
}

// ---------------- main GEMM: out = A'[T][KP] @ B'[OUT][KP]^T ----------------
// XOR-swizzled LDS: row r, 16B-chunk c stored at chunk slot c^(r&7).
__global__ __launch_bounds__(256) void k_gemm(const u16* __restrict__ A,
                                              const u16* __restrict__ B,
                                              float* __restrict__ C) {
  __shared__ u16 sA[128 * 64];
  __shared__ u16 sB[128 * 64];
  int tid = threadIdx.x;
  int wave = tid >> 6, lane = tid & 63;
  int quad = lane >> 4, l16 = lane & 15;
  int wr = wave >> 1, wc = wave & 1;
  int t0 = blockIdx.x * 128;
  int o0 = blockIdx.y * 128;
  f32x4 acc[4][4];
  for (int i = 0; i < 4; ++i)
    for (int j = 0; j < 4; ++j)
      acc[i][j] = (f32x4){0.f, 0.f, 0.f, 0.f};
  const u16* gA = A + (size_t)t0 * KP;
  const u16* gB = B + (size_t)o0 * KP;
  for (int k0 = 0; k0 < KP; k0 += 64) {
    __syncthreads();
#pragma unroll
    for (int r = 0; r < 4; ++r) {
      int off = r * 4096 + wave * 1024 + lane * 16;  // LDS byte offset
      int row = off >> 7;                            // 128B rows
      int sc = ((off >> 4) & 7) ^ (row & 7);         // swizzled source chunk
      int kw = sc * 8;
      __builtin_amdgcn_global_load_lds(
          (gas_u32*)(const void*)(gA + (size_t)row * KP + k0 + kw),
          (las_u32*)(void*)((char*)sA + off), 16, 0, 0);
      __builtin_amdgcn_global_load_lds(
          (gas_u32*)(const void*)(gB + (size_t)row * KP + k0 + kw),
          (las_u32*)(void*)((char*)sB + off), 16, 0, 0);
    }
    __syncthreads();
#pragma unroll
    for (int kk = 0; kk < 2; ++kk) {
      short8 af[4], bf[4];
#pragma unroll
      for (int i = 0; i < 4; ++i) {
        int row = wr * 64 + i * 16 + l16;
        int sc = (kk * 4 + quad) ^ (l16 & 7);
        af[i] = *(const short8*)(sA + row * 64 + sc * 8);
      }
#pragma unroll
      for (int j = 0; j < 4; ++j) {
        int row = wc * 64 + j * 16 + l16;
        int sc = (kk * 4 + quad) ^ (l16 & 7);
        bf[j] = *(const short8*)(sB + row * 64 + sc * 8);
      }
#pragma unroll
      for (int i = 0; i < 4; ++i)
#pragma unroll
        for (int j = 0; j < 4; ++j)
          acc[i][j] = __builtin_amdgcn_mfma_f32_16x16x32_bf16(af[i], bf[j], acc[i][j], 0, 0, 0);
    }
  }
#pragma unroll
  for (int i = 0; i < 4; ++i) {
    int row = t0 + wr * 64 + i * 16 + quad * 4;
#pragma unroll
    for (int j = 0; j < 4; ++j) {
      int col = o0 + wc * 64 + j * 16 + l16;
#pragma unroll
      for (int e = 0; e < 4; ++e)
        C[(size_t)(row + e) * OUT_DIM + col] = acc[i][j][e];
    }
  }
}

extern "C" void kernel_launch(void* const* d_in, const int* in_sizes, int n_in,
                              void* d_out, int out_size, void* d_ws, size_t ws_size,
                              hipStream_t stream) {
  const float* x      = (const float*)d_in[0];
  const int*   qw     = (const int*)d_in[1];
  const float* wsc    = (const float*)d_in[2];
  const float* smooth = (const float*)d_in[3];
  const float* pd     = (const float*)d_in[4];
  const float* pu     = (const float*)d_in[5];
  float* out = (float*)d_out;

  char* ws = (char*)d_ws;
  u16* A   = (u16*)ws;                                     // 68,157,440 B
  u16* B   = (u16*)(ws + 68157440);                        // 34,078,720 B
  u16* pdT = (u16*)(ws + 68157440 + 34078720);             // 262,144 B

  k_wdq  <<<dim3(OUT_DIM * 4), dim3(256), 0, stream>>>(qw, wsc, B);
  k_wlora<<<dim3(OUT_DIM * 64 / 256), dim3(256), 0, stream>>>(pu, B);
  k_prep <<<dim3(IN_DIM * RANK / 256), dim3(256), 0, stream>>>(pd, pdT);
  k_act  <<<dim3(T_DIM / 16), dim3(256), 0, stream>>>(x, smooth, pdT, A);
  k_gemm <<<dim3(T_DIM / 128, OUT_DIM / 128), dim3(256), 0, stream>>>(A, B, out);
}